// Round 25
// baseline (132.130 us; speedup 1.0000x reference)
//
#include <hip/hip_runtime.h>
#include <hip/hip_bf16.h>

typedef __attribute__((ext_vector_type(8))) short short8;
typedef __attribute__((ext_vector_type(4))) short short4v;
typedef __attribute__((ext_vector_type(4))) float floatx4;
typedef unsigned short u16;

__device__ __forceinline__ float b2f(u16 u) {
    unsigned int x = ((unsigned int)u) << 16;
    float f;
    __builtin_memcpy(&f, &x, 4);
    return f;
}
__device__ __forceinline__ u16 f2b(float f) {
    unsigned int x;
    __builtin_memcpy(&x, &f, 4);
    unsigned int lsb = (x >> 16) & 1u;
    x += 0x7fffu + lsb;
    return (u16)(x >> 16);
}
// truncating fp32 -> bf16 (positive values; high half of the float bits). ~1 VALU.
__device__ __forceinline__ u16 f2b_hi(float f) {
    unsigned int x;
    __builtin_memcpy(&x, &f, 4);
    return (u16)(x >> 16);
}

// async global->LDS, 16B per lane; LDS dest = wave-uniform base + lane*16 [m97]
__device__ __forceinline__ void gload16(const u16* g, u16* l) {
    __builtin_amdgcn_global_load_lds(
        (const __attribute__((address_space(1))) void*)g,
        (__attribute__((address_space(3))) void*)l,
        16, 0, 0);
}

// ------------- ALL transposes (fp32->bf16) + x cast in ONE launch -------------
__global__ __launch_bounds__(256) void transpose_all(const float* __restrict__ clip,
                                                     const float* __restrict__ conv_w,
                                                     const float* __restrict__ w0,
                                                     const float* __restrict__ w1,
                                                     const float* __restrict__ w2,
                                                     const float* __restrict__ w3,
                                                     const float* __restrict__ x,
                                                     u16* __restrict__ clipT,
                                                     u16* __restrict__ convwT,
                                                     u16* __restrict__ wT,
                                                     u16* __restrict__ xb) {
    int id = blockIdx.x;
    if (id >= 5120) {
        int i = (id - 5120) * 256 + threadIdx.x;
        float4 f0 = ((const float4*)x)[i * 2];
        float4 f1 = ((const float4*)x)[i * 2 + 1];
        short8 s;
        s[0] = (short)f2b(f0.x); s[1] = (short)f2b(f0.y);
        s[2] = (short)f2b(f0.z); s[3] = (short)f2b(f0.w);
        s[4] = (short)f2b(f1.x); s[5] = (short)f2b(f1.y);
        s[6] = (short)f2b(f1.z); s[7] = (short)f2b(f1.w);
        ((short8*)xb)[i] = s;
        return;
    }
    __shared__ float tile[32][33];
    const float* ip;
    u16* op;
    int R, C, c0, r0;
    if (id < 2048) {
        int b = id >> 8, rem = id & 255;
        R = 1024; C = 256;
        c0 = (rem & 7) * 32; r0 = (rem >> 3) * 32;
        ip = clip + (long)b * 262144;
        op = clipT + (long)b * 262144;
    } else if (id < 2816) {
        int i2 = id - 2048;
        R = 1024; C = 768;
        c0 = (i2 % 24) * 32; r0 = (i2 / 24) * 32;
        ip = conv_w;
        op = convwT;
    } else {
        int i3 = id - 2816;
        int z = i3 / 576, rem = i3 % 576;
        R = 768; C = 768;
        c0 = (rem % 24) * 32; r0 = (rem / 24) * 32;
        ip = (z == 0) ? w0 : (z == 1) ? w1 : (z == 2) ? w2 : w3;
        op = wT + (long)z * 589824;
    }
    int tx = threadIdx.x & 31, ty = threadIdx.x >> 5;
    for (int j = 0; j < 32; j += 8)
        tile[ty + j][tx] = ip[(long)(r0 + ty + j) * C + c0 + tx];
    __syncthreads();
    for (int j = 0; j < 32; j += 8)
        op[(long)(c0 + ty + j) * R + r0 + tx] = f2b(tile[tx][ty + j]);
}

// ---- GEMM 128x64, BK=64, gload_lds staging (r16-proven, 0 conflicts): Q/O projections ----
__global__ __launch_bounds__(256) void gemm_ld64(const u16* __restrict__ A,
                                                 const u16* __restrict__ Bt,
                                                 const float* __restrict__ bias,
                                                 u16* __restrict__ Cv,
                                                 int M, int N, int K, int ldc,
                                                 float oscale) {
    __shared__ __align__(16) u16 lA[128 * 64];   // 16 KB
    __shared__ __align__(16) u16 lB[64 * 64];    // 8 KB
    int tid = threadIdx.x, lane = tid & 63, w = tid >> 6;
    int m0 = blockIdx.x * 128, n0 = blockIdx.y * 64;
    floatx4 acc[2][4] = {};
    const int lr = lane & 15, kg = lane >> 4;
    int rt = tid >> 3, sl = ((tid & 7) ^ (rt & 7)) * 8;
    const u16* gA0 = &A[(long)(m0 + rt) * K + sl];
    const u16* gA1 = &A[(long)(m0 + 32 + rt) * K + sl];
    const u16* gA2 = &A[(long)(m0 + 64 + rt) * K + sl];
    const u16* gA3 = &A[(long)(m0 + 96 + rt) * K + sl];
    const u16* gB0 = &Bt[(long)(n0 + rt) * K + sl];
    const u16* gB1 = &Bt[(long)(n0 + 32 + rt) * K + sl];
    const int s0 = (kg ^ (lr & 7)) * 8;
    for (int k0 = 0; k0 < K; k0 += 64) {
        gload16(gA0 + k0, &lA[w * 512]);
        gload16(gA1 + k0, &lA[2048 + w * 512]);
        gload16(gA2 + k0, &lA[4096 + w * 512]);
        gload16(gA3 + k0, &lA[6144 + w * 512]);
        gload16(gB0 + k0, &lB[w * 512]);
        gload16(gB1 + k0, &lB[2048 + w * 512]);
        __syncthreads();
        #pragma unroll
        for (int ks = 0; ks < 2; ks++) {
            int sseg = s0 ^ (ks << 5);
            short8 a0 = *(const short8*)&lA[(w * 32 + lr) * 64 + sseg];
            short8 a1 = *(const short8*)&lA[(w * 32 + 16 + lr) * 64 + sseg];
            #pragma unroll
            for (int ni = 0; ni < 4; ni++) {
                short8 bf = *(const short8*)&lB[(ni * 16 + lr) * 64 + sseg];
                acc[0][ni] = __builtin_amdgcn_mfma_f32_16x16x32_bf16(a0, bf, acc[0][ni], 0, 0, 0);
                acc[1][ni] = __builtin_amdgcn_mfma_f32_16x16x32_bf16(a1, bf, acc[1][ni], 0, 0, 0);
            }
        }
        __syncthreads();
    }
    #pragma unroll
    for (int mi = 0; mi < 2; mi++)
        #pragma unroll
        for (int ni = 0; ni < 4; ni++) {
            int n = n0 + ni * 16 + lr;
            float bv = bias[n];
            #pragma unroll
            for (int r = 0; r < 4; r++) {
                int m = m0 + w * 32 + mi * 16 + kg * 4 + r;
                Cv[(long)m * ldc + n] = f2b((acc[mi][ni][r] + bv) * oscale);
            }
        }
}

// ---- MERGED launch: blocks [0,768) = fused K|V projection (128x128, all-gload, r17-proven);
//      blocks [768,960) = conv GEMM (128x64, r16-proven). Independent inputs, shared LDS pool.
__global__ __launch_bounds__(256) void gemm_convkv(const u16* __restrict__ xb,
                                                   const u16* __restrict__ wkvT,
                                                   const float* __restrict__ bk,
                                                   const float* __restrict__ bv,
                                                   u16* __restrict__ kb,
                                                   u16* __restrict__ vTout,
                                                   const u16* __restrict__ clipT,
                                                   const u16* __restrict__ convwT,
                                                   const float* __restrict__ conv_b,
                                                   u16* __restrict__ t_lo) {
    __shared__ __align__(16) u16 lA[128 * 64];   // 16 KB
    __shared__ __align__(16) u16 lB[128 * 64];   // 16 KB
    int tid = threadIdx.x, lane = tid & 63, w = tid >> 6;
    const int lr = lane & 15, kg = lane >> 4;
    int rt = tid >> 3, sl = ((tid & 7) ^ (rt & 7)) * 8;
    const int s0 = (kg ^ (lr & 7)) * 8;
    int id = blockIdx.x;
    if (id < 768) {
        const int K = 768;
        int wr = w >> 1, wc = w & 1;
        int m0 = (id & 63) * 128, n0 = (id >> 6) * 128;
        floatx4 acc[4][4] = {};
        const u16* gA0 = &xb[(long)(m0 + rt) * K + sl];
        const u16* gA1 = &xb[(long)(m0 + 32 + rt) * K + sl];
        const u16* gA2 = &xb[(long)(m0 + 64 + rt) * K + sl];
        const u16* gA3 = &xb[(long)(m0 + 96 + rt) * K + sl];
        const u16* gB0 = &wkvT[(long)(n0 + rt) * K + sl];
        const u16* gB1 = &wkvT[(long)(n0 + 32 + rt) * K + sl];
        const u16* gB2 = &wkvT[(long)(n0 + 64 + rt) * K + sl];
        const u16* gB3 = &wkvT[(long)(n0 + 96 + rt) * K + sl];
        for (int k0 = 0; k0 < K; k0 += 64) {
            gload16(gA0 + k0, &lA[w * 512]);
            gload16(gA1 + k0, &lA[2048 + w * 512]);
            gload16(gA2 + k0, &lA[4096 + w * 512]);
            gload16(gA3 + k0, &lA[6144 + w * 512]);
            gload16(gB0 + k0, &lB[w * 512]);
            gload16(gB1 + k0, &lB[2048 + w * 512]);
            gload16(gB2 + k0, &lB[4096 + w * 512]);
            gload16(gB3 + k0, &lB[6144 + w * 512]);
            __syncthreads();
            #pragma unroll
            for (int ks = 0; ks < 2; ks++) {
                int sseg = s0 ^ (ks << 5);
                short8 af[4], bf[4];
                #pragma unroll
                for (int mi = 0; mi < 4; mi++)
                    af[mi] = *(const short8*)&lA[(wr * 64 + mi * 16 + lr) * 64 + sseg];
                #pragma unroll
                for (int ni = 0; ni < 4; ni++)
                    bf[ni] = *(const short8*)&lB[(wc * 64 + ni * 16 + lr) * 64 + sseg];
                #pragma unroll
                for (int mi = 0; mi < 4; mi++)
                    #pragma unroll
                    for (int ni = 0; ni < 4; ni++)
                        acc[mi][ni] = __builtin_amdgcn_mfma_f32_16x16x32_bf16(af[mi], bf[ni], acc[mi][ni], 0, 0, 0);
            }
            __syncthreads();
        }
        #pragma unroll
        for (int mi = 0; mi < 4; mi++)
            #pragma unroll
            for (int ni = 0; ni < 4; ni++) {
                int n = n0 + wc * 64 + ni * 16 + lr;
                float bvv = (n < 768) ? bk[n] : bv[n - 768];
                if (n >= 768) {
                    int fg = n - 768;
                    int h = fg / 96, f = fg - h * 96;
                    int mb = m0 + wr * 64 + mi * 16 + kg * 4;
                    long vrow = ((long)((m0 >> 10) * 8 + h) * 96 + f) * 1024 + (mb & 1023);
                    short4v pk;
                    #pragma unroll
                    for (int r = 0; r < 4; r++) pk[r] = (short)f2b(acc[mi][ni][r] + bvv);
                    *(short4v*)&vTout[vrow] = pk;
                } else {
                    #pragma unroll
                    for (int r = 0; r < 4; r++) {
                        int m = m0 + wr * 64 + mi * 16 + kg * 4 + r;
                        kb[(long)m * 768 + n] = f2b(acc[mi][ni][r] + bvv);
                    }
                }
            }
    } else {
        const int K = 1024;
        int id2 = id - 768;
        int m0 = (id2 & 15) * 128, n0 = (id2 >> 4) * 64;
        floatx4 acc[2][4] = {};
        const u16* gA0 = &clipT[(long)(m0 + rt) * K + sl];
        const u16* gA1 = &clipT[(long)(m0 + 32 + rt) * K + sl];
        const u16* gA2 = &clipT[(long)(m0 + 64 + rt) * K + sl];
        const u16* gA3 = &clipT[(long)(m0 + 96 + rt) * K + sl];
        const u16* gB0 = &convwT[(long)(n0 + rt) * K + sl];
        const u16* gB1 = &convwT[(long)(n0 + 32 + rt) * K + sl];
        for (int k0 = 0; k0 < K; k0 += 64) {
            gload16(gA0 + k0, &lA[w * 512]);
            gload16(gA1 + k0, &lA[2048 + w * 512]);
            gload16(gA2 + k0, &lA[4096 + w * 512]);
            gload16(gA3 + k0, &lA[6144 + w * 512]);
            gload16(gB0 + k0, &lB[w * 512]);
            gload16(gB1 + k0, &lB[2048 + w * 512]);
            __syncthreads();
            #pragma unroll
            for (int ks = 0; ks < 2; ks++) {
                int sseg = s0 ^ (ks << 5);
                short8 a0 = *(const short8*)&lA[(w * 32 + lr) * 64 + sseg];
                short8 a1 = *(const short8*)&lA[(w * 32 + 16 + lr) * 64 + sseg];
                #pragma unroll
                for (int ni = 0; ni < 4; ni++) {
                    short8 bf = *(const short8*)&lB[(ni * 16 + lr) * 64 + sseg];
                    acc[0][ni] = __builtin_amdgcn_mfma_f32_16x16x32_bf16(a0, bf, acc[0][ni], 0, 0, 0);
                    acc[1][ni] = __builtin_amdgcn_mfma_f32_16x16x32_bf16(a1, bf, acc[1][ni], 0, 0, 0);
                }
            }
            __syncthreads();
        }
        #pragma unroll
        for (int mi = 0; mi < 2; mi++)
            #pragma unroll
            for (int ni = 0; ni < 4; ni++) {
                int n = n0 + ni * 16 + lr;
                float bvv = conv_b[n];
                #pragma unroll
                for (int r = 0; r < 4; r++) {
                    int m = m0 + w * 32 + mi * 16 + kg * 4 + r;
                    t_lo[(long)m * 768 + n] = f2b(acc[mi][ni][r] + bvv);
                }
            }
    }
}

// --------- bilinear-resize (16->32) + channel-first LN, one wave per pixel (no LDS) ---------
__global__ __launch_bounds__(256) void ln1_resize_w(const u16* __restrict__ t_lo,
                                                    const float* __restrict__ lnw,
                                                    const float* __restrict__ lnb,
                                                    u16* __restrict__ q_in) {
    int wv = threadIdx.x >> 6, lane = threadIdx.x & 63;
    int b = blockIdx.z, oh = blockIdx.y, ow = blockIdx.x * 4 + wv;
    float sy = oh * 0.5f - 0.25f;
    int iy = (int)floorf(sy);
    float fy = sy - (float)iy;
    int y0 = min(max(iy, 0), 15), y1 = min(max(iy + 1, 0), 15);
    float sx = ow * 0.5f - 0.25f;
    int ix = (int)floorf(sx);
    float fx = sx - (float)ix;
    int x0 = min(max(ix, 0), 15), x1 = min(max(ix + 1, 0), 15);
    float w00 = (1.f - fy) * (1.f - fx), w01 = (1.f - fy) * fx;
    float w10 = fy * (1.f - fx), w11 = fy * fx;
    long base = (long)b * 256 * 768;
    long i00 = base + (long)(y0 * 16 + x0) * 768;
    long i01 = base + (long)(y0 * 16 + x1) * 768;
    long i10 = base + (long)(y1 * 16 + x0) * 768;
    long i11 = base + (long)(y1 * 16 + x1) * 768;
    float v[12];
    float s = 0.f, sq = 0.f;
    #pragma unroll
    for (int j = 0; j < 3; j++) {
        int c0 = (j * 64 + lane) * 4;
        short4v a = *(const short4v*)&t_lo[i00 + c0];
        short4v c = *(const short4v*)&t_lo[i01 + c0];
        short4v d = *(const short4v*)&t_lo[i10 + c0];
        short4v e = *(const short4v*)&t_lo[i11 + c0];
        #pragma unroll
        for (int k = 0; k < 4; k++) {
            float val = w00 * b2f((u16)a[k]) + w01 * b2f((u16)c[k]) +
                        w10 * b2f((u16)d[k]) + w11 * b2f((u16)e[k]);
            v[j * 4 + k] = val;
            s += val;
            sq += val * val;
        }
    }
    #pragma unroll
    for (int off = 32; off >= 1; off >>= 1) {
        s += __shfl_xor(s, off);
        sq += __shfl_xor(sq, off);
    }
    float mean = s * (1.f / 768.f);
    float var = sq * (1.f / 768.f) - mean * mean;
    float rstd = rsqrtf(var + 1e-6f);
    long orow = ((long)b * 1024 + oh * 32 + ow) * 768;
    #pragma unroll
    for (int j = 0; j < 3; j++) {
        int c0 = (j * 64 + lane) * 4;
        float4 w4 = *(const float4*)&lnw[c0];
        float4 b4 = *(const float4*)&lnb[c0];
        short4v o;
        o[0] = (short)f2b((v[j * 4 + 0] - mean) * rstd * w4.x + b4.x);
        o[1] = (short)f2b((v[j * 4 + 1] - mean) * rstd * w4.y + b4.y);
        o[2] = (short)f2b((v[j * 4 + 2] - mean) * rstd * w4.z + b4.z);
        o[3] = (short)f2b((v[j * 4 + 3] - mean) * rstd * w4.w + b4.w);
        *(short4v*)&q_in[orow + c0] = o;
    }
}

// ---------------- flash attention: r22 pipeline + setprio; PP=78 (odd stride) and
// truncating high-half P stores (denominator still accumulates fp32 values) ----
#define PP 78
__global__ __launch_bounds__(512) void attn_kernel(const u16* __restrict__ Q,
                                                   const u16* __restrict__ Km,
                                                   const u16* __restrict__ Vt,
                                                   u16* __restrict__ O) {
    __shared__ __align__(16) u16 lK[2 * 4096];   // 16 KB  [64][64] x2
    __shared__ __align__(16) u16 lKb[2 * 2048];  //  8 KB  [64][32] x2
    __shared__ __align__(16) u16 lV[2 * 6144];   // 24 KB  [96][64] x2
    __shared__ __align__(16) u16 lP[128 * PP];   // 19.5 KB
    int tid = threadIdx.x, lane = tid & 63, w = tid >> 6;
    int L = blockIdx.x + (blockIdx.y << 3) + (blockIdx.z << 6);
    int b = L & 7, h = (L >> 3) & 7, qt = L >> 6;
    const int lr = lane & 15, kg = lane >> 4;

    long qrow = ((long)b * 1024 + qt * 128 + w * 16 + lr) * 768 + h * 96;
    short8 aq[3];
    for (int ks = 0; ks < 3; ks++) aq[ks] = *(const short8*)&Q[qrow + ks * 32 + kg * 8];

    floatx4 acco[6] = {};
    float lrun[4] = {0.f, 0.f, 0.f, 0.f};

    long kvbase = ((long)b * 1024) * 768 + h * 96;
    long vtbase = ((long)(b * 8 + h)) * 96 * 1024;

    const u16* gp[3];
    u16* lp[3];
    int gs[3], bs[3];
    #pragma unroll
    for (int i = 0; i < 3; i++) {
        int id = tid + i * 512;
        if (id < 512) {
            int row = id >> 3, lg = (id & 7) ^ (row & 7);
            lp[i] = &lK[id * 8];
            gp[i] = &Km[kvbase + (long)row * 768 + lg * 8];
            gs[i] = 64 * 768;
            bs[i] = 4096;
        } else if (id < 768) {
            int j = id - 512;
            int row = j >> 2, lg = (j & 3) ^ (row & 3);
            lp[i] = &lKb[j * 8];
            gp[i] = &Km[kvbase + (long)row * 768 + 64 + lg * 8];
            gs[i] = 64 * 768;
            bs[i] = 2048;
        } else {
            int j = id - 768;
            int f = j >> 3, lg = (j & 7) ^ (f & 7);
            lp[i] = &lV[j * 8];
            gp[i] = &Vt[vtbase + (long)f * 1024 + lg * 8];
            gs[i] = 64;
            bs[i] = 6144;
        }
    }

    const int sA = (kg ^ (lr & 7)) * 8;
    const int sB = (kg ^ (lr & 3)) * 8;

    // prologue: tile 0 -> buffer 0 (left in flight; waited inside the loop)
    #pragma unroll
    for (int i = 0; i < 3; i++) {
        gload16(gp[i], lp[i]);
        gp[i] += gs[i];
    }

    for (int kt = 0; kt < 16; kt++) {
        int cur = kt & 1, nxt = cur ^ 1;
        if (kt < 15) {
            #pragma unroll
            for (int i = 0; i < 3; i++) {
                gload16(gp[i], lp[i] + nxt * bs[i]);
                gp[i] += gs[i];
            }
            asm volatile("s_waitcnt vmcnt(3)" ::: "memory");
        } else {
            asm volatile("s_waitcnt vmcnt(0)" ::: "memory");
        }
        __builtin_amdgcn_sched_barrier(0);
        __builtin_amdgcn_s_barrier();     // all waves: T(kt) visible in LDS

        const u16* K0 = &lK[cur * 4096];
        const u16* Kb0 = &lKb[cur * 2048];
        const u16* V0 = &lV[cur * 6144];

        floatx4 accs[4] = {};
        __builtin_amdgcn_s_setprio(1);
        for (int ni = 0; ni < 4; ni++) {
            int rb = (ni * 16 + lr);
            short8 bk0 = *(const short8*)&K0[rb * 64 + sA];
            short8 bk1 = *(const short8*)&K0[rb * 64 + (sA ^ 32)];
            short8 bk2 = *(const short8*)&Kb0[rb * 32 + sB];
            accs[ni] = __builtin_amdgcn_mfma_f32_16x16x32_bf16(aq[0], bk0, accs[ni], 0, 0, 0);
            accs[ni] = __builtin_amdgcn_mfma_f32_16x16x32_bf16(aq[1], bk1, accs[ni], 0, 0, 0);
            accs[ni] = __builtin_amdgcn_mfma_f32_16x16x32_bf16(aq[2], bk2, accs[ni], 0, 0, 0);
        }
        __builtin_amdgcn_s_setprio(0);

        for (int r = 0; r < 4; r++) {
            float p0 = __builtin_amdgcn_exp2f(accs[0][r]);
            float p1 = __builtin_amdgcn_exp2f(accs[1][r]);
            float p2 = __builtin_amdgcn_exp2f(accs[2][r]);
            float p3 = __builtin_amdgcn_exp2f(accs[3][r]);
            lrun[r] += (p0 + p1) + (p2 + p3);
            int prow = w * 16 + kg * 4 + r;
            lP[prow * PP + 0 + lr] = f2b_hi(p0);
            lP[prow * PP + 16 + lr] = f2b_hi(p1);
            lP[prow * PP + 32 + lr] = f2b_hi(p2);
            lP[prow * PP + 48 + lr] = f2b_hi(p3);
        }

        short8 ap0 = *(const short8*)&lP[(w * 16 + lr) * PP + kg * 8];
        short8 ap1 = *(const short8*)&lP[(w * 16 + lr) * PP + 32 + kg * 8];
        __builtin_amdgcn_s_setprio(1);
        for (int nb = 0; nb < 6; nb++) {
            int fb = (nb * 16 + lr);
            short8 bv0 = *(const short8*)&V0[fb * 64 + sA];
            short8 bv1 = *(const short8*)&V0[fb * 64 + (sA ^ 32)];
            acco[nb] = __builtin_amdgcn_mfma_f32_16x16x32_bf16(ap0, bv0, acco[nb], 0, 0, 0);
            acco[nb] = __builtin_amdgcn_mfma_f32_16x16x32_bf16(ap1, bv1, acco[nb], 0, 0, 0);
        }
        __builtin_amdgcn_s_setprio(0);
        __builtin_amdgcn_s_barrier();     // all waves done reading buf cur -> may be overwritten
    }

    #pragma unroll
    for (int r = 0; r < 4; r++)
        for (int off = 1; off < 16; off <<= 1) lrun[r] += __shfl_xor(lrun[r], off);
    float invl[4];
    #pragma unroll
    for (int r = 0; r < 4; r++) invl[r] = 1.0f / lrun[r];

    long obase = ((long)b * 1024 + qt * 128 + w * 16) * 768 + h * 96;
    for (int nb = 0; nb < 6; nb++)
        for (int r = 0; r < 4; r++) {
            float val = acco[nb][r] * invl[r];
            O[obase + (long)(kg * 4 + r) * 768 + nb * 16 + lr] = f2b(val);
        }
}

// -------- LayerNorm (eps 1e-5): read bf16, write fp32, one wave per row (no LDS) --------
__global__ __launch_bounds__(256) void ln2_w(const u16* __restrict__ o,
                                             const float* __restrict__ lnw,
                                             const float* __restrict__ lnb,
                                             float* __restrict__ out) {
    int wv = threadIdx.x >> 6, lane = threadIdx.x & 63;
    long row = (long)blockIdx.x * 4 + wv;
    long base = row * 768;
    float v[12];
    float s = 0.f, sq = 0.f;
    #pragma unroll
    for (int j = 0; j < 3; j++) {
        int c0 = (j * 64 + lane) * 4;
        short4v a = *(const short4v*)&o[base + c0];
        #pragma unroll
        for (int k = 0; k < 4; k++) {
            float val = b2f((u16)a[k]);
            v[j * 4 + k] = val;
            s += val;
            sq += val * val;
        }
    }
    #pragma unroll
    for (int off = 32; off >= 1; off >>= 1) {
        s += __shfl_xor(s, off);
        sq += __shfl_xor(sq, off);
    }
    float mean = s * (1.f / 768.f);
    float var = sq * (1.f / 768.f) - mean * mean;
    float rstd = rsqrtf(var + 1e-5f);
    #pragma unroll
    for (int j = 0; j < 3; j++) {
        int c0 = (j * 64 + lane) * 4;
        float4 w4 = *(const float4*)&lnw[c0];
        float4 b4 = *(const float4*)&lnb[c0];
        float4 r4;
        r4.x = (v[j * 4 + 0] - mean) * rstd * w4.x + b4.x;
        r4.y = (v[j * 4 + 1] - mean) * rstd * w4.y + b4.y;
        r4.z = (v[j * 4 + 2] - mean) * rstd * w4.z + b4.z;
        r4.w = (v[j * 4 + 3] - mean) * rstd * w4.w + b4.w;
        *(float4*)&out[base + c0] = r4;
    }
}

extern "C" void kernel_launch(void* const* d_in, const int* in_sizes, int n_in,
                              void* d_out, int out_size, void* d_ws, size_t ws_size,
                              hipStream_t stream) {
    const float* x       = (const float*)d_in[0];
    const float* clip    = (const float*)d_in[1];
    const float* conv_w  = (const float*)d_in[2];
    const float* conv_b  = (const float*)d_in[3];
    const float* ln1_w   = (const float*)d_in[4];
    const float* ln1_b   = (const float*)d_in[5];
    const float* wq      = (const float*)d_in[6];
    const float* bq      = (const float*)d_in[7];
    const float* wk      = (const float*)d_in[8];
    const float* bk      = (const float*)d_in[9];
    const float* wv      = (const float*)d_in[10];
    const float* bv      = (const float*)d_in[11];
    const float* wo      = (const float*)d_in[12];
    const float* bo      = (const float*)d_in[13];
    const float* ln2_w_  = (const float*)d_in[14];
    const float* ln2_b_  = (const float*)d_in[15];
    float* out = (float*)d_out;

    u16* ws = (u16*)d_ws;
    u16* clipT   = ws;
    u16* convwT  = clipT + 2097152;
    u16* wqT     = convwT + 786432;              // wq/wk/wv/wo transposed, contiguous
    u16* wkT     = wqT + 589824;
    u16* wvT     = wkT + 589824;
    u16* woT     = wvT + 589824;
    u16* t_lo    = woT + 589824;
    u16* q_in    = t_lo + 1572864;               // attn output aliases this after kvproj
    u16* qb      = q_in + 6291456;               // Q; reused as o-proj output
    u16* kb      = qb + 6291456;                 // K: 8192 x 768
    u16* vT      = kb + 6291456;                 // V^T per head: 64 x 96 x 1024
    u16* xb      = vT + 6291456;                 // bf16 x (dedicated slot; filled upfront)
    u16* attno   = q_in;
    u16* obuf    = qb;

    // Q pre-scale folds softmax scale AND log2(e) so attn uses exp2 directly.
    const float QSCALE = 0.10206207261596575f * 1.4426950408889634f;

    // 1) all transposes + x cast in one launch
    transpose_all<<<8192, 256, 0, stream>>>(clip, conv_w, wq, wk, wv, wo, x,
                                            clipT, convwT, wqT, xb);

    // 2) MERGED conv + fused K|V projection (both depend only on transpose_all)
    gemm_convkv<<<960, 256, 0, stream>>>(xb, wkT, bk, bv, kb, vT,
                                         clipT, convwT, conv_b, t_lo);

    // 3) bilinear resize + channel-first LN -> q_in
    ln1_resize_w<<<dim3(8, 32, 8), 256, 0, stream>>>(t_lo, ln1_w, ln1_b, q_in);

    // 4) Q projection (BK=64 gload, scaled) -> qb
    gemm_ld64<<<dim3(64, 12), 256, 0, stream>>>(q_in, wqT, bq, qb, 8192, 768, 768, 768, QSCALE);

    // 5) attention (counted-vmcnt pipeline + setprio; PP=78, truncating P stores) -> attno
    attn_kernel<<<dim3(8, 8, 8), 512, 0, stream>>>(qb, kb, vT, attno);

    // 6) out projection (BK=64 gload) -> bf16 obuf
    gemm_ld64<<<dim3(64, 12), 256, 0, stream>>>(attno, woT, bo, obuf, 8192, 768, 768, 768, 1.0f);

    // 7) LayerNorm: bf16 obuf -> fp32 d_out
    ln2_w<<<2048, 256, 0, stream>>>(obuf, ln2_w_, ln2_b_, out);
}

// Round 26
// 130.210 us; speedup vs baseline: 1.0147x; 1.0147x over previous
//
#include <hip/hip_runtime.h>
#include <hip/hip_bf16.h>

typedef __attribute__((ext_vector_type(8))) short short8;
typedef __attribute__((ext_vector_type(4))) short short4v;
typedef __attribute__((ext_vector_type(4))) float floatx4;
typedef unsigned short u16;

__device__ __forceinline__ float b2f(u16 u) {
    unsigned int x = ((unsigned int)u) << 16;
    float f;
    __builtin_memcpy(&f, &x, 4);
    return f;
}
__device__ __forceinline__ u16 f2b(float f) {
    unsigned int x;
    __builtin_memcpy(&x, &f, 4);
    unsigned int lsb = (x >> 16) & 1u;
    x += 0x7fffu + lsb;
    return (u16)(x >> 16);
}
// truncating fp32 -> bf16 (positive values; high half of the float bits). ~1 VALU.
__device__ __forceinline__ u16 f2b_hi(float f) {
    unsigned int x;
    __builtin_memcpy(&x, &f, 4);
    return (u16)(x >> 16);
}

// async global->LDS, 16B per lane; LDS dest = wave-uniform base + lane*16 [m97]
__device__ __forceinline__ void gload16(const u16* g, u16* l) {
    __builtin_amdgcn_global_load_lds(
        (const __attribute__((address_space(1))) void*)g,
        (__attribute__((address_space(3))) void*)l,
        16, 0, 0);
}

// ------------- ALL transposes (fp32->bf16) + x cast in ONE launch -------------
__global__ __launch_bounds__(256) void transpose_all(const float* __restrict__ clip,
                                                     const float* __restrict__ conv_w,
                                                     const float* __restrict__ w0,
                                                     const float* __restrict__ w1,
                                                     const float* __restrict__ w2,
                                                     const float* __restrict__ w3,
                                                     const float* __restrict__ x,
                                                     u16* __restrict__ clipT,
                                                     u16* __restrict__ convwT,
                                                     u16* __restrict__ wT,
                                                     u16* __restrict__ xb) {
    int id = blockIdx.x;
    if (id >= 5120) {
        int i = (id - 5120) * 256 + threadIdx.x;
        float4 f0 = ((const float4*)x)[i * 2];
        float4 f1 = ((const float4*)x)[i * 2 + 1];
        short8 s;
        s[0] = (short)f2b(f0.x); s[1] = (short)f2b(f0.y);
        s[2] = (short)f2b(f0.z); s[3] = (short)f2b(f0.w);
        s[4] = (short)f2b(f1.x); s[5] = (short)f2b(f1.y);
        s[6] = (short)f2b(f1.z); s[7] = (short)f2b(f1.w);
        ((short8*)xb)[i] = s;
        return;
    }
    __shared__ float tile[32][33];
    const float* ip;
    u16* op;
    int R, C, c0, r0;
    if (id < 2048) {
        int b = id >> 8, rem = id & 255;
        R = 1024; C = 256;
        c0 = (rem & 7) * 32; r0 = (rem >> 3) * 32;
        ip = clip + (long)b * 262144;
        op = clipT + (long)b * 262144;
    } else if (id < 2816) {
        int i2 = id - 2048;
        R = 1024; C = 768;
        c0 = (i2 % 24) * 32; r0 = (i2 / 24) * 32;
        ip = conv_w;
        op = convwT;
    } else {
        int i3 = id - 2816;
        int z = i3 / 576, rem = i3 % 576;
        R = 768; C = 768;
        c0 = (rem % 24) * 32; r0 = (rem / 24) * 32;
        ip = (z == 0) ? w0 : (z == 1) ? w1 : (z == 2) ? w2 : w3;
        op = wT + (long)z * 589824;
    }
    int tx = threadIdx.x & 31, ty = threadIdx.x >> 5;
    for (int j = 0; j < 32; j += 8)
        tile[ty + j][tx] = ip[(long)(r0 + ty + j) * C + c0 + tx];
    __syncthreads();
    for (int j = 0; j < 32; j += 8)
        op[(long)(c0 + ty + j) * R + r0 + tx] = f2b(tile[tx][ty + j]);
}

// ---- GEMM 128x64, BK=64, gload_lds staging (r16-proven, 0 conflicts): Q/O projections ----
__global__ __launch_bounds__(256) void gemm_ld64(const u16* __restrict__ A,
                                                 const u16* __restrict__ Bt,
                                                 const float* __restrict__ bias,
                                                 u16* __restrict__ Cv,
                                                 int M, int N, int K, int ldc,
                                                 float oscale) {
    __shared__ __align__(16) u16 lA[128 * 64];   // 16 KB
    __shared__ __align__(16) u16 lB[64 * 64];    // 8 KB
    int tid = threadIdx.x, lane = tid & 63, w = tid >> 6;
    int m0 = blockIdx.x * 128, n0 = blockIdx.y * 64;
    floatx4 acc[2][4] = {};
    const int lr = lane & 15, kg = lane >> 4;
    int rt = tid >> 3, sl = ((tid & 7) ^ (rt & 7)) * 8;
    const u16* gA0 = &A[(long)(m0 + rt) * K + sl];
    const u16* gA1 = &A[(long)(m0 + 32 + rt) * K + sl];
    const u16* gA2 = &A[(long)(m0 + 64 + rt) * K + sl];
    const u16* gA3 = &A[(long)(m0 + 96 + rt) * K + sl];
    const u16* gB0 = &Bt[(long)(n0 + rt) * K + sl];
    const u16* gB1 = &Bt[(long)(n0 + 32 + rt) * K + sl];
    const int s0 = (kg ^ (lr & 7)) * 8;
    for (int k0 = 0; k0 < K; k0 += 64) {
        gload16(gA0 + k0, &lA[w * 512]);
        gload16(gA1 + k0, &lA[2048 + w * 512]);
        gload16(gA2 + k0, &lA[4096 + w * 512]);
        gload16(gA3 + k0, &lA[6144 + w * 512]);
        gload16(gB0 + k0, &lB[w * 512]);
        gload16(gB1 + k0, &lB[2048 + w * 512]);
        __syncthreads();
        #pragma unroll
        for (int ks = 0; ks < 2; ks++) {
            int sseg = s0 ^ (ks << 5);
            short8 a0 = *(const short8*)&lA[(w * 32 + lr) * 64 + sseg];
            short8 a1 = *(const short8*)&lA[(w * 32 + 16 + lr) * 64 + sseg];
            #pragma unroll
            for (int ni = 0; ni < 4; ni++) {
                short8 bf = *(const short8*)&lB[(ni * 16 + lr) * 64 + sseg];
                acc[0][ni] = __builtin_amdgcn_mfma_f32_16x16x32_bf16(a0, bf, acc[0][ni], 0, 0, 0);
                acc[1][ni] = __builtin_amdgcn_mfma_f32_16x16x32_bf16(a1, bf, acc[1][ni], 0, 0, 0);
            }
        }
        __syncthreads();
    }
    #pragma unroll
    for (int mi = 0; mi < 2; mi++)
        #pragma unroll
        for (int ni = 0; ni < 4; ni++) {
            int n = n0 + ni * 16 + lr;
            float bv = bias[n];
            #pragma unroll
            for (int r = 0; r < 4; r++) {
                int m = m0 + w * 32 + mi * 16 + kg * 4 + r;
                Cv[(long)m * ldc + n] = f2b((acc[mi][ni][r] + bv) * oscale);
            }
        }
}

// ---- MERGED launch: blocks [0,768) = fused K|V projection (128x128, all-gload, r17-proven);
//      blocks [768,960) = conv GEMM (128x64, r16-proven). Independent inputs, shared LDS pool.
__global__ __launch_bounds__(256) void gemm_convkv(const u16* __restrict__ xb,
                                                   const u16* __restrict__ wkvT,
                                                   const float* __restrict__ bk,
                                                   const float* __restrict__ bv,
                                                   u16* __restrict__ kb,
                                                   u16* __restrict__ vTout,
                                                   const u16* __restrict__ clipT,
                                                   const u16* __restrict__ convwT,
                                                   const float* __restrict__ conv_b,
                                                   u16* __restrict__ t_lo) {
    __shared__ __align__(16) u16 lA[128 * 64];   // 16 KB
    __shared__ __align__(16) u16 lB[128 * 64];   // 16 KB
    int tid = threadIdx.x, lane = tid & 63, w = tid >> 6;
    const int lr = lane & 15, kg = lane >> 4;
    int rt = tid >> 3, sl = ((tid & 7) ^ (rt & 7)) * 8;
    const int s0 = (kg ^ (lr & 7)) * 8;
    int id = blockIdx.x;
    if (id < 768) {
        const int K = 768;
        int wr = w >> 1, wc = w & 1;
        int m0 = (id & 63) * 128, n0 = (id >> 6) * 128;
        floatx4 acc[4][4] = {};
        const u16* gA0 = &xb[(long)(m0 + rt) * K + sl];
        const u16* gA1 = &xb[(long)(m0 + 32 + rt) * K + sl];
        const u16* gA2 = &xb[(long)(m0 + 64 + rt) * K + sl];
        const u16* gA3 = &xb[(long)(m0 + 96 + rt) * K + sl];
        const u16* gB0 = &wkvT[(long)(n0 + rt) * K + sl];
        const u16* gB1 = &wkvT[(long)(n0 + 32 + rt) * K + sl];
        const u16* gB2 = &wkvT[(long)(n0 + 64 + rt) * K + sl];
        const u16* gB3 = &wkvT[(long)(n0 + 96 + rt) * K + sl];
        for (int k0 = 0; k0 < K; k0 += 64) {
            gload16(gA0 + k0, &lA[w * 512]);
            gload16(gA1 + k0, &lA[2048 + w * 512]);
            gload16(gA2 + k0, &lA[4096 + w * 512]);
            gload16(gA3 + k0, &lA[6144 + w * 512]);
            gload16(gB0 + k0, &lB[w * 512]);
            gload16(gB1 + k0, &lB[2048 + w * 512]);
            gload16(gB2 + k0, &lB[4096 + w * 512]);
            gload16(gB3 + k0, &lB[6144 + w * 512]);
            __syncthreads();
            #pragma unroll
            for (int ks = 0; ks < 2; ks++) {
                int sseg = s0 ^ (ks << 5);
                short8 af[4], bf[4];
                #pragma unroll
                for (int mi = 0; mi < 4; mi++)
                    af[mi] = *(const short8*)&lA[(wr * 64 + mi * 16 + lr) * 64 + sseg];
                #pragma unroll
                for (int ni = 0; ni < 4; ni++)
                    bf[ni] = *(const short8*)&lB[(wc * 64 + ni * 16 + lr) * 64 + sseg];
                #pragma unroll
                for (int mi = 0; mi < 4; mi++)
                    #pragma unroll
                    for (int ni = 0; ni < 4; ni++)
                        acc[mi][ni] = __builtin_amdgcn_mfma_f32_16x16x32_bf16(af[mi], bf[ni], acc[mi][ni], 0, 0, 0);
            }
            __syncthreads();
        }
        #pragma unroll
        for (int mi = 0; mi < 4; mi++)
            #pragma unroll
            for (int ni = 0; ni < 4; ni++) {
                int n = n0 + wc * 64 + ni * 16 + lr;
                float bvv = (n < 768) ? bk[n] : bv[n - 768];
                if (n >= 768) {
                    int fg = n - 768;
                    int h = fg / 96, f = fg - h * 96;
                    int mb = m0 + wr * 64 + mi * 16 + kg * 4;
                    long vrow = ((long)((m0 >> 10) * 8 + h) * 96 + f) * 1024 + (mb & 1023);
                    short4v pk;
                    #pragma unroll
                    for (int r = 0; r < 4; r++) pk[r] = (short)f2b(acc[mi][ni][r] + bvv);
                    *(short4v*)&vTout[vrow] = pk;
                } else {
                    #pragma unroll
                    for (int r = 0; r < 4; r++) {
                        int m = m0 + wr * 64 + mi * 16 + kg * 4 + r;
                        kb[(long)m * 768 + n] = f2b(acc[mi][ni][r] + bvv);
                    }
                }
            }
    } else {
        const int K = 1024;
        int id2 = id - 768;
        int m0 = (id2 & 15) * 128, n0 = (id2 >> 4) * 64;
        floatx4 acc[2][4] = {};
        const u16* gA0 = &clipT[(long)(m0 + rt) * K + sl];
        const u16* gA1 = &clipT[(long)(m0 + 32 + rt) * K + sl];
        const u16* gA2 = &clipT[(long)(m0 + 64 + rt) * K + sl];
        const u16* gA3 = &clipT[(long)(m0 + 96 + rt) * K + sl];
        const u16* gB0 = &convwT[(long)(n0 + rt) * K + sl];
        const u16* gB1 = &convwT[(long)(n0 + 32 + rt) * K + sl];
        for (int k0 = 0; k0 < K; k0 += 64) {
            gload16(gA0 + k0, &lA[w * 512]);
            gload16(gA1 + k0, &lA[2048 + w * 512]);
            gload16(gA2 + k0, &lA[4096 + w * 512]);
            gload16(gA3 + k0, &lA[6144 + w * 512]);
            gload16(gB0 + k0, &lB[w * 512]);
            gload16(gB1 + k0, &lB[2048 + w * 512]);
            __syncthreads();
            #pragma unroll
            for (int ks = 0; ks < 2; ks++) {
                int sseg = s0 ^ (ks << 5);
                short8 a0 = *(const short8*)&lA[(w * 32 + lr) * 64 + sseg];
                short8 a1 = *(const short8*)&lA[(w * 32 + 16 + lr) * 64 + sseg];
                #pragma unroll
                for (int ni = 0; ni < 4; ni++) {
                    short8 bf = *(const short8*)&lB[(ni * 16 + lr) * 64 + sseg];
                    acc[0][ni] = __builtin_amdgcn_mfma_f32_16x16x32_bf16(a0, bf, acc[0][ni], 0, 0, 0);
                    acc[1][ni] = __builtin_amdgcn_mfma_f32_16x16x32_bf16(a1, bf, acc[1][ni], 0, 0, 0);
                }
            }
            __syncthreads();
        }
        #pragma unroll
        for (int mi = 0; mi < 2; mi++)
            #pragma unroll
            for (int ni = 0; ni < 4; ni++) {
                int n = n0 + ni * 16 + lr;
                float bvv = conv_b[n];
                #pragma unroll
                for (int r = 0; r < 4; r++) {
                    int m = m0 + w * 32 + mi * 16 + kg * 4 + r;
                    t_lo[(long)m * 768 + n] = f2b(acc[mi][ni][r] + bvv);
                }
            }
    }
}

// --------- bilinear-resize (16->32) + channel-first LN, one wave per pixel (no LDS) ---------
__global__ __launch_bounds__(256) void ln1_resize_w(const u16* __restrict__ t_lo,
                                                    const float* __restrict__ lnw,
                                                    const float* __restrict__ lnb,
                                                    u16* __restrict__ q_in) {
    int wv = threadIdx.x >> 6, lane = threadIdx.x & 63;
    int b = blockIdx.z, oh = blockIdx.y, ow = blockIdx.x * 4 + wv;
    float sy = oh * 0.5f - 0.25f;
    int iy = (int)floorf(sy);
    float fy = sy - (float)iy;
    int y0 = min(max(iy, 0), 15), y1 = min(max(iy + 1, 0), 15);
    float sx = ow * 0.5f - 0.25f;
    int ix = (int)floorf(sx);
    float fx = sx - (float)ix;
    int x0 = min(max(ix, 0), 15), x1 = min(max(ix + 1, 0), 15);
    float w00 = (1.f - fy) * (1.f - fx), w01 = (1.f - fy) * fx;
    float w10 = fy * (1.f - fx), w11 = fy * fx;
    long base = (long)b * 256 * 768;
    long i00 = base + (long)(y0 * 16 + x0) * 768;
    long i01 = base + (long)(y0 * 16 + x1) * 768;
    long i10 = base + (long)(y1 * 16 + x0) * 768;
    long i11 = base + (long)(y1 * 16 + x1) * 768;
    float v[12];
    float s = 0.f, sq = 0.f;
    #pragma unroll
    for (int j = 0; j < 3; j++) {
        int c0 = (j * 64 + lane) * 4;
        short4v a = *(const short4v*)&t_lo[i00 + c0];
        short4v c = *(const short4v*)&t_lo[i01 + c0];
        short4v d = *(const short4v*)&t_lo[i10 + c0];
        short4v e = *(const short4v*)&t_lo[i11 + c0];
        #pragma unroll
        for (int k = 0; k < 4; k++) {
            float val = w00 * b2f((u16)a[k]) + w01 * b2f((u16)c[k]) +
                        w10 * b2f((u16)d[k]) + w11 * b2f((u16)e[k]);
            v[j * 4 + k] = val;
            s += val;
            sq += val * val;
        }
    }
    #pragma unroll
    for (int off = 32; off >= 1; off >>= 1) {
        s += __shfl_xor(s, off);
        sq += __shfl_xor(sq, off);
    }
    float mean = s * (1.f / 768.f);
    float var = sq * (1.f / 768.f) - mean * mean;
    float rstd = rsqrtf(var + 1e-6f);
    long orow = ((long)b * 1024 + oh * 32 + ow) * 768;
    #pragma unroll
    for (int j = 0; j < 3; j++) {
        int c0 = (j * 64 + lane) * 4;
        float4 w4 = *(const float4*)&lnw[c0];
        float4 b4 = *(const float4*)&lnb[c0];
        short4v o;
        o[0] = (short)f2b((v[j * 4 + 0] - mean) * rstd * w4.x + b4.x);
        o[1] = (short)f2b((v[j * 4 + 1] - mean) * rstd * w4.y + b4.y);
        o[2] = (short)f2b((v[j * 4 + 2] - mean) * rstd * w4.z + b4.z);
        o[3] = (short)f2b((v[j * 4 + 3] - mean) * rstd * w4.w + b4.w);
        *(short4v*)&q_in[orow + c0] = o;
    }
}

// ---------------- flash attention: r22 pipeline + setprio; PP=76 (measured-best) with
// truncating high-half P stores (denominator still accumulates fp32 values) ----
#define PP 76
__global__ __launch_bounds__(512) void attn_kernel(const u16* __restrict__ Q,
                                                   const u16* __restrict__ Km,
                                                   const u16* __restrict__ Vt,
                                                   u16* __restrict__ O) {
    __shared__ __align__(16) u16 lK[2 * 4096];   // 16 KB  [64][64] x2
    __shared__ __align__(16) u16 lKb[2 * 2048];  //  8 KB  [64][32] x2
    __shared__ __align__(16) u16 lV[2 * 6144];   // 24 KB  [96][64] x2
    __shared__ __align__(16) u16 lP[128 * PP];   // 19 KB
    int tid = threadIdx.x, lane = tid & 63, w = tid >> 6;
    int L = blockIdx.x + (blockIdx.y << 3) + (blockIdx.z << 6);
    int b = L & 7, h = (L >> 3) & 7, qt = L >> 6;
    const int lr = lane & 15, kg = lane >> 4;

    long qrow = ((long)b * 1024 + qt * 128 + w * 16 + lr) * 768 + h * 96;
    short8 aq[3];
    for (int ks = 0; ks < 3; ks++) aq[ks] = *(const short8*)&Q[qrow + ks * 32 + kg * 8];

    floatx4 acco[6] = {};
    float lrun[4] = {0.f, 0.f, 0.f, 0.f};

    long kvbase = ((long)b * 1024) * 768 + h * 96;
    long vtbase = ((long)(b * 8 + h)) * 96 * 1024;

    const u16* gp[3];
    u16* lp[3];
    int gs[3], bs[3];
    #pragma unroll
    for (int i = 0; i < 3; i++) {
        int id = tid + i * 512;
        if (id < 512) {
            int row = id >> 3, lg = (id & 7) ^ (row & 7);
            lp[i] = &lK[id * 8];
            gp[i] = &Km[kvbase + (long)row * 768 + lg * 8];
            gs[i] = 64 * 768;
            bs[i] = 4096;
        } else if (id < 768) {
            int j = id - 512;
            int row = j >> 2, lg = (j & 3) ^ (row & 3);
            lp[i] = &lKb[j * 8];
            gp[i] = &Km[kvbase + (long)row * 768 + 64 + lg * 8];
            gs[i] = 64 * 768;
            bs[i] = 2048;
        } else {
            int j = id - 768;
            int f = j >> 3, lg = (j & 7) ^ (f & 7);
            lp[i] = &lV[j * 8];
            gp[i] = &Vt[vtbase + (long)f * 1024 + lg * 8];
            gs[i] = 64;
            bs[i] = 6144;
        }
    }

    const int sA = (kg ^ (lr & 7)) * 8;
    const int sB = (kg ^ (lr & 3)) * 8;

    // prologue: tile 0 -> buffer 0 (left in flight; waited inside the loop)
    #pragma unroll
    for (int i = 0; i < 3; i++) {
        gload16(gp[i], lp[i]);
        gp[i] += gs[i];
    }

    for (int kt = 0; kt < 16; kt++) {
        int cur = kt & 1, nxt = cur ^ 1;
        if (kt < 15) {
            #pragma unroll
            for (int i = 0; i < 3; i++) {
                gload16(gp[i], lp[i] + nxt * bs[i]);
                gp[i] += gs[i];
            }
            asm volatile("s_waitcnt vmcnt(3)" ::: "memory");
        } else {
            asm volatile("s_waitcnt vmcnt(0)" ::: "memory");
        }
        __builtin_amdgcn_sched_barrier(0);
        __builtin_amdgcn_s_barrier();     // all waves: T(kt) visible in LDS

        const u16* K0 = &lK[cur * 4096];
        const u16* Kb0 = &lKb[cur * 2048];
        const u16* V0 = &lV[cur * 6144];

        floatx4 accs[4] = {};
        __builtin_amdgcn_s_setprio(1);
        for (int ni = 0; ni < 4; ni++) {
            int rb = (ni * 16 + lr);
            short8 bk0 = *(const short8*)&K0[rb * 64 + sA];
            short8 bk1 = *(const short8*)&K0[rb * 64 + (sA ^ 32)];
            short8 bk2 = *(const short8*)&Kb0[rb * 32 + sB];
            accs[ni] = __builtin_amdgcn_mfma_f32_16x16x32_bf16(aq[0], bk0, accs[ni], 0, 0, 0);
            accs[ni] = __builtin_amdgcn_mfma_f32_16x16x32_bf16(aq[1], bk1, accs[ni], 0, 0, 0);
            accs[ni] = __builtin_amdgcn_mfma_f32_16x16x32_bf16(aq[2], bk2, accs[ni], 0, 0, 0);
        }
        __builtin_amdgcn_s_setprio(0);

        for (int r = 0; r < 4; r++) {
            float p0 = __builtin_amdgcn_exp2f(accs[0][r]);
            float p1 = __builtin_amdgcn_exp2f(accs[1][r]);
            float p2 = __builtin_amdgcn_exp2f(accs[2][r]);
            float p3 = __builtin_amdgcn_exp2f(accs[3][r]);
            lrun[r] += (p0 + p1) + (p2 + p3);
            int prow = w * 16 + kg * 4 + r;
            lP[prow * PP + 0 + lr] = f2b_hi(p0);
            lP[prow * PP + 16 + lr] = f2b_hi(p1);
            lP[prow * PP + 32 + lr] = f2b_hi(p2);
            lP[prow * PP + 48 + lr] = f2b_hi(p3);
        }

        short8 ap0 = *(const short8*)&lP[(w * 16 + lr) * PP + kg * 8];
        short8 ap1 = *(const short8*)&lP[(w * 16 + lr) * PP + 32 + kg * 8];
        __builtin_amdgcn_s_setprio(1);
        for (int nb = 0; nb < 6; nb++) {
            int fb = (nb * 16 + lr);
            short8 bv0 = *(const short8*)&V0[fb * 64 + sA];
            short8 bv1 = *(const short8*)&V0[fb * 64 + (sA ^ 32)];
            acco[nb] = __builtin_amdgcn_mfma_f32_16x16x32_bf16(ap0, bv0, acco[nb], 0, 0, 0);
            acco[nb] = __builtin_amdgcn_mfma_f32_16x16x32_bf16(ap1, bv1, acco[nb], 0, 0, 0);
        }
        __builtin_amdgcn_s_setprio(0);
        __builtin_amdgcn_s_barrier();     // all waves done reading buf cur -> may be overwritten
    }

    #pragma unroll
    for (int r = 0; r < 4; r++)
        for (int off = 1; off < 16; off <<= 1) lrun[r] += __shfl_xor(lrun[r], off);
    float invl[4];
    #pragma unroll
    for (int r = 0; r < 4; r++) invl[r] = 1.0f / lrun[r];

    long obase = ((long)b * 1024 + qt * 128 + w * 16) * 768 + h * 96;
    for (int nb = 0; nb < 6; nb++)
        for (int r = 0; r < 4; r++) {
            float val = acco[nb][r] * invl[r];
            O[obase + (long)(kg * 4 + r) * 768 + nb * 16 + lr] = f2b(val);
        }
}

// -------- LayerNorm (eps 1e-5): read bf16, write fp32, one wave per row (no LDS) --------
__global__ __launch_bounds__(256) void ln2_w(const u16* __restrict__ o,
                                             const float* __restrict__ lnw,
                                             const float* __restrict__ lnb,
                                             float* __restrict__ out) {
    int wv = threadIdx.x >> 6, lane = threadIdx.x & 63;
    long row = (long)blockIdx.x * 4 + wv;
    long base = row * 768;
    float v[12];
    float s = 0.f, sq = 0.f;
    #pragma unroll
    for (int j = 0; j < 3; j++) {
        int c0 = (j * 64 + lane) * 4;
        short4v a = *(const short4v*)&o[base + c0];
        #pragma unroll
        for (int k = 0; k < 4; k++) {
            float val = b2f((u16)a[k]);
            v[j * 4 + k] = val;
            s += val;
            sq += val * val;
        }
    }
    #pragma unroll
    for (int off = 32; off >= 1; off >>= 1) {
        s += __shfl_xor(s, off);
        sq += __shfl_xor(sq, off);
    }
    float mean = s * (1.f / 768.f);
    float var = sq * (1.f / 768.f) - mean * mean;
    float rstd = rsqrtf(var + 1e-5f);
    #pragma unroll
    for (int j = 0; j < 3; j++) {
        int c0 = (j * 64 + lane) * 4;
        float4 w4 = *(const float4*)&lnw[c0];
        float4 b4 = *(const float4*)&lnb[c0];
        float4 r4;
        r4.x = (v[j * 4 + 0] - mean) * rstd * w4.x + b4.x;
        r4.y = (v[j * 4 + 1] - mean) * rstd * w4.y + b4.y;
        r4.z = (v[j * 4 + 2] - mean) * rstd * w4.z + b4.z;
        r4.w = (v[j * 4 + 3] - mean) * rstd * w4.w + b4.w;
        *(float4*)&out[base + c0] = r4;
    }
}

extern "C" void kernel_launch(void* const* d_in, const int* in_sizes, int n_in,
                              void* d_out, int out_size, void* d_ws, size_t ws_size,
                              hipStream_t stream) {
    const float* x       = (const float*)d_in[0];
    const float* clip    = (const float*)d_in[1];
    const float* conv_w  = (const float*)d_in[2];
    const float* conv_b  = (const float*)d_in[3];
    const float* ln1_w   = (const float*)d_in[4];
    const float* ln1_b   = (const float*)d_in[5];
    const float* wq      = (const float*)d_in[6];
    const float* bq      = (const float*)d_in[7];
    const float* wk      = (const float*)d_in[8];
    const float* bk      = (const float*)d_in[9];
    const float* wv      = (const float*)d_in[10];
    const float* bv      = (const float*)d_in[11];
    const float* wo      = (const float*)d_in[12];
    const float* bo      = (const float*)d_in[13];
    const float* ln2_w_  = (const float*)d_in[14];
    const float* ln2_b_  = (const float*)d_in[15];
    float* out = (float*)d_out;

    u16* ws = (u16*)d_ws;
    u16* clipT   = ws;
    u16* convwT  = clipT + 2097152;
    u16* wqT     = convwT + 786432;              // wq/wk/wv/wo transposed, contiguous
    u16* wkT     = wqT + 589824;
    u16* wvT     = wkT + 589824;
    u16* woT     = wvT + 589824;
    u16* t_lo    = woT + 589824;
    u16* q_in    = t_lo + 1572864;               // attn output aliases this after kvproj
    u16* qb      = q_in + 6291456;               // Q; reused as o-proj output
    u16* kb      = qb + 6291456;                 // K: 8192 x 768
    u16* vT      = kb + 6291456;                 // V^T per head: 64 x 96 x 1024
    u16* xb      = vT + 6291456;                 // bf16 x (dedicated slot; filled upfront)
    u16* attno   = q_in;
    u16* obuf    = qb;

    // Q pre-scale folds softmax scale AND log2(e) so attn uses exp2 directly.
    const float QSCALE = 0.10206207261596575f * 1.4426950408889634f;

    // 1) all transposes + x cast in one launch
    transpose_all<<<8192, 256, 0, stream>>>(clip, conv_w, wq, wk, wv, wo, x,
                                            clipT, convwT, wqT, xb);

    // 2) MERGED conv + fused K|V projection (both depend only on transpose_all)
    gemm_convkv<<<960, 256, 0, stream>>>(xb, wkT, bk, bv, kb, vT,
                                         clipT, convwT, conv_b, t_lo);

    // 3) bilinear resize + channel-first LN -> q_in
    ln1_resize_w<<<dim3(8, 32, 8), 256, 0, stream>>>(t_lo, ln1_w, ln1_b, q_in);

    // 4) Q projection (BK=64 gload, scaled) -> qb
    gemm_ld64<<<dim3(64, 12), 256, 0, stream>>>(q_in, wqT, bq, qb, 8192, 768, 768, 768, QSCALE);

    // 5) attention (counted-vmcnt pipeline + setprio; PP=76, truncating P stores) -> attno
    attn_kernel<<<dim3(8, 8, 8), 512, 0, stream>>>(qb, kb, vT, attno);

    // 6) out projection (BK=64 gload) -> bf16 obuf
    gemm_ld64<<<dim3(64, 12), 256, 0, stream>>>(attno, woT, bo, obuf, 8192, 768, 768, 768, 1.0f);

    // 7) LayerNorm: bf16 obuf -> fp32 d_out
    ln2_w<<<2048, 256, 0, stream>>>(obuf, ln2_w_, ln2_b_, out);
}